// Round 1
// baseline (865.752 us; speedup 1.0000x reference)
//
#include <hip/hip_runtime.h>

// Monte-Carlo (stochastic) 2x2 pooling.
// Reference: per 2x2 block, idx = argmax_k( log(max(x_k,EPS)) + gumbel(u_k) ),
//            gumbel(u) = -log(-log(clip(u, EPS, 1-EPS))).
// Monotone-transform equivalence: argmax of log(x'_k) - log(w_k) with
// w_k = -log(clip(u_k)) > 0  ==  argmax of x'_k / w_k.
// Resolved via cross-multiplication in double (exact to ~1e-16 rel), which
// preserves argmax's first-index tie-breaking with a strict '>' ascending scan.
//
// Shapes: x (32,64,224,224) f32, u (32,64,112,112,4) f32, out (32,64,112,112) f32.

#define PH 112
#define PW 112
#define EPS 1e-12

__global__ __launch_bounds__(256) void mc_pool_kernel(const float* __restrict__ x,
                                                      const float* __restrict__ u,
                                                      float* __restrict__ out,
                                                      int n_out) {
    int o = blockIdx.x * blockDim.x + threadIdx.x;
    if (o >= n_out) return;

    int j  = o % PW;          // pooled col
    int t  = o / PW;
    int i  = t % PH;          // pooled row
    int bc = t / PH;          // fused batch*channel

    // x as float2: each (b,c) image is 224*224 floats = 25088 float2;
    // row r starts at float2 offset bc*25088 + r*112. Block rows 2i, 2i+1.
    const float2* __restrict__ x2 = (const float2*)x;
    long base = (long)bc * 25088 + (long)i * 224 + j;
    float2 ra = x2[base];         // x[2i][2j], x[2i][2j+1]
    float2 rb = x2[base + 112];   // x[2i+1][2j], x[2i+1][2j+1]

    // u: 4 contiguous floats per output, same (p0,p1) flatten order as block.
    const float4* __restrict__ u4p = (const float4*)u;
    float4 uu = u4p[o];

    double xv[4] = { fmax((double)ra.x, EPS), fmax((double)ra.y, EPS),
                     fmax((double)rb.x, EPS), fmax((double)rb.y, EPS) };
    double uv[4] = { (double)uu.x, (double)uu.y, (double)uu.z, (double)uu.w };

    double w[4];
#pragma unroll
    for (int k = 0; k < 4; ++k) {
        double uc = fmin(fmax(uv[k], EPS), 1.0 - EPS);
        w[k] = -log(uc);   // > 0 since uc < 1
    }

    // argmax_k xv[k]/w[k] via cross-multiplication; strict '>' keeps lowest
    // index on ties, matching jnp.argmax.
    int best = 0;
#pragma unroll
    for (int k = 1; k < 4; ++k) {
        if (xv[k] * w[best] > xv[best] * w[k]) best = k;
    }

    out[o] = (float)best;
}

extern "C" void kernel_launch(void* const* d_in, const int* in_sizes, int n_in,
                              void* d_out, int out_size, void* d_ws, size_t ws_size,
                              hipStream_t stream) {
    const float* x = (const float*)d_in[0];
    const float* u = (const float*)d_in[1];
    float* out = (float*)d_out;
    int n_out = out_size;  // 32*64*112*112 = 25,690,112
    int block = 256;
    int grid = (n_out + block - 1) / block;
    mc_pool_kernel<<<grid, block, 0, stream>>>(x, u, out, n_out);
}